// Round 4
// baseline (13132.607 us; speedup 1.0000x reference)
//
#include <hip/hip_runtime.h>
#include <hip/hip_bf16.h>
#include <cstdint>

#define TT 128
#define BB 64
#define II 1024
#define HD 4096
#define N_IH 262144
#define N_HH 1048576
#define LN_EPS 1e-5f
#define NREP 16
#define GRIDN 1024

typedef unsigned int u32;
typedef unsigned short u16;
typedef float f32x2 __attribute__((ext_vector_type(2)));

__device__ __forceinline__ u32 f2bf_bits(float f) {
  u32 u = __float_as_uint(f);
  return (u + 0x7FFFu + ((u >> 16) & 1u)) >> 16;   // RTNE, finite inputs
}

// ---------------- preprocessing (no global atomics) ----------------

__global__ __launch_bounds__(256) void k_hist2(const int* __restrict__ rows, int n,
                                               int* __restrict__ histG) {
  __shared__ int histL[HD];
  int blk = blockIdx.x, chunk = n >> 8;
  for (int i = threadIdx.x; i < HD; i += 256) histL[i] = 0;
  __syncthreads();
  const int* p = rows + blk * chunk;
  for (int i = threadIdx.x; i < chunk; i += 256) atomicAdd(&histL[p[i]], 1);
  __syncthreads();
  for (int r = threadIdx.x; r < HD; r += 256) histG[r * 256 + blk] = histL[r];
}

__global__ __launch_bounds__(256) void k_rowtot2(const int* __restrict__ histG,
                                                 int* __restrict__ rowtot) {
  int w = threadIdx.x >> 6, lane = threadIdx.x & 63;
  int row = blockIdx.x * 4 + w;
  int c = 0;
#pragma unroll
  for (int j = 0; j < 4; ++j) c += histG[row * 256 + j * 64 + lane];
#pragma unroll
  for (int d = 1; d < 64; d <<= 1) c += __shfl_xor(c, d);
  if (lane == 0) rowtot[row] = (c + 7) & ~7;
}

__global__ void k_scan2(const int* __restrict__ rowtot, int* __restrict__ rp) {
  int lane = threadIdx.x;
  int total = 0;
  for (int j = 0; j < 64; ++j) total += rowtot[lane * 64 + j];
  int x = total;
  for (int d = 1; d < 64; d <<= 1) {
    int y = __shfl_up(x, d, 64);
    if (lane >= d) x += y;
  }
  int run = x - total;
  for (int j = 0; j < 64; ++j) {
    int idx = lane * 64 + j;
    rp[idx] = run;
    run += rowtot[idx];
  }
  if (lane == 63) rp[HD] = run;
}

__global__ __launch_bounds__(256) void k_repbase2(const int* __restrict__ histG,
                                                  const int* __restrict__ rp,
                                                  int* __restrict__ curG) {
  int w = threadIdx.x >> 6, lane = threadIdx.x & 63;
  int row = blockIdx.x * 4 + w;
  const int* h = histG + row * 256 + lane * 4;
  int v0 = h[0], v1 = h[1], v2 = h[2], v3 = h[3];
  int s = v0 + v1 + v2 + v3;
  int x = s;
#pragma unroll
  for (int d = 1; d < 64; d <<= 1) {
    int y = __shfl_up(x, d);
    if (lane >= d) x += y;
  }
  int base = rp[row] + x - s;
  int* o = curG + row * 256 + lane * 4;
  o[0] = base;
  o[1] = base + v0;
  o[2] = base + v0 + v1;
  o[3] = base + v0 + v1 + v2;
}

__global__ __launch_bounds__(256) void k_scatter2(
    const int* __restrict__ rows, const int* __restrict__ cols,
    const float* __restrict__ vals, int n, const int* __restrict__ curG,
    u32* __restrict__ meta, u16* __restrict__ metb,
    const float* __restrict__ gamma, const float* __restrict__ beta, int fold) {
  __shared__ int curL[HD];
  int blk = blockIdx.x, chunk = n >> 8;
  for (int r = threadIdx.x; r < HD; r += 256) curL[r] = curG[r * 256 + blk];
  __syncthreads();
  int e0 = blk * chunk;
  for (int i = threadIdx.x; i < chunk; i += 256) {
    int e = e0 + i;
    int r = rows[e], c = cols[e];
    float v = vals[e];
    float vg = fold ? v * gamma[c] : v;
    int pos = atomicAdd(&curL[r], 1);
    meta[pos] = (f2bf_bits(vg) << 16) | (u32)c;
    if (fold) metb[pos] = (u16)f2bf_bits(v * beta[c]);
  }
}

__global__ __launch_bounds__(256) void k_rvred2(const u32* __restrict__ meta,
                                                const u16* __restrict__ metb,
                                                const int* __restrict__ rp,
                                                float* __restrict__ rowvg,
                                                float* __restrict__ rowvb) {
  int w = threadIdx.x >> 6, lane = threadIdx.x & 63;
  int row = blockIdx.x * 4 + w;
  int s = rp[row], e = rp[row + 1];
  float a = 0.f, b = 0.f;
  for (int i = s + lane; i < e; i += 64) {
    a += __uint_as_float(meta[i] & 0xFFFF0000u);
    b += __uint_as_float(((u32)metb[i]) << 16);
  }
#pragma unroll
  for (int d = 1; d < 64; d <<= 1) { a += __shfl_xor(a, d); b += __shfl_xor(b, d); }
  if (lane == 0) { rowvg[row] = a; rowvb[row] = b; }
}

__global__ __launch_bounds__(256) void k_xt(const float* __restrict__ x, u16* __restrict__ xt) {
  __shared__ u16 tile[64][66];
  int t = blockIdx.x >> 4, i0 = (blockIdx.x & 15) << 6;
  int w = threadIdx.x >> 6, lane = threadIdx.x & 63;
#pragma unroll
  for (int k = 0; k < 16; ++k) {
    int b = w * 16 + k;
    float v = x[((size_t)b * TT + t) * II + i0 + lane];
    tile[b][lane] = (u16)f2bf_bits(v);
  }
  __syncthreads();
#pragma unroll
  for (int k = 0; k < 16; ++k) {
    int i = w * 16 + k;
    xt[((size_t)t * II + i0 + i) * BB + lane] = tile[lane][i];
  }
}

// ---------------- gather core ----------------

__device__ __forceinline__ uint4 gld(const char* base, u32 m) {
  return *(const uint4*)(base + ((int)(m & 0xFFFFu) << 7));
}

__device__ __forceinline__ void consume(u32 m, uint4 g, f32x2 acc[4]) {
  float vgf = __uint_as_float(m & 0xFFFF0000u);
  f32x2 vg2 = {vgf, vgf};
  f32x2 p0 = {__uint_as_float(g.x << 16), __uint_as_float(g.x & 0xFFFF0000u)};
  f32x2 p1 = {__uint_as_float(g.y << 16), __uint_as_float(g.y & 0xFFFF0000u)};
  f32x2 p2 = {__uint_as_float(g.z << 16), __uint_as_float(g.z & 0xFFFF0000u)};
  f32x2 p3 = {__uint_as_float(g.w << 16), __uint_as_float(g.w & 0xFFFF0000u)};
  acc[0] += vg2 * p0;
  acc[1] += vg2 * p1;
  acc[2] += vg2 * p2;
  acc[3] += vg2 * p3;
}

__device__ __forceinline__ void gather8(const u32* __restrict__ meta, int s0, int n,
                                        const char* __restrict__ base, f32x2 acc[4]) {
  if (n <= 0) return;
  const u32* mp = meta + s0 + ((threadIdx.x & 63) >> 3);
  u32 m0 = mp[0], m1 = mp[8], m2 = mp[16], m3 = mp[24];
  uint4 g0 = gld(base, m0), g1 = gld(base, m1), g2 = gld(base, m2);
  for (int it = 0; it < n; ++it) {
    u32 m4 = mp[(it + 4) * 8];          // slack reads stay inside zeroed padding
    uint4 g3 = gld(base, m3);
    consume(m0, g0, acc);
    m0 = m1; m1 = m2; m2 = m3; m3 = m4;
    g0 = g1; g1 = g2; g2 = g3;
  }
}

// ---------------- explicit grid barrier ----------------

__device__ __forceinline__ void grid_bar(u32* bar, u32 target) {
  __syncthreads();
  if (threadIdx.x == 0) {
    // release: writes back dirty L2 (publishes A stores + stats atomics)
    __hip_atomic_fetch_add(bar, 1u, __ATOMIC_RELEASE, __HIP_MEMORY_SCOPE_AGENT);
    while (__hip_atomic_load(bar, __ATOMIC_RELAXED, __HIP_MEMORY_SCOPE_AGENT) < target)
      __builtin_amdgcn_s_sleep(2);
    // acquire: invalidate local caches
    (void)__hip_atomic_load(bar, __ATOMIC_ACQUIRE, __HIP_MEMORY_SCOPE_AGENT);
  }
  __syncthreads();
}

// ---------------- fused time-loop (cooperative co-residency, own barrier) ----------------

__global__ __launch_bounds__(256, 4) void k_mega(
    const u32* __restrict__ meta_ih, const int* __restrict__ rp_ih,
    const u32* __restrict__ meta_hh, const int* __restrict__ rp_hh,
    const u16* __restrict__ xt, u16* __restrict__ A, float* __restrict__ stats,
    const float* __restrict__ b_ih, const float* __restrict__ b_hh,
    const float* __restrict__ rowvg, const float* __restrict__ rowvb,
    u32* __restrict__ bar) {
  __shared__ float s_mu[64], s_rs[64], s_sum[64], s_sq[64];
  __shared__ float epil[4][2][64];
  int tid = threadIdx.x, w = tid >> 6, lane = tid & 63;
  int row = blockIdx.x * 4 + w;
  int s0i = rp_ih[row], ni = (rp_ih[row + 1] - s0i) >> 3;
  int s0h = rp_hh[row], nh = (rp_hh[row + 1] - s0h) >> 3;
  float rvg = rowvg[row], rvb = rowvb[row];
  float bsum = b_ih[row] + b_hh[row];
  int l = lane & 7;
  int rep = blockIdx.x & (NREP - 1);
  if (tid < 64) { s_mu[tid] = 0.f; s_rs[tid] = 1.f; }

  for (int t = 0; t < TT; ++t) {
    float sacc = 0.f, qacc = 0.f;
    if (t && tid >= 64 && tid < 128) {
      const float* st_prev = stats + (size_t)(t - 1) * (2 * NREP * 64);
      int b = tid - 64;
#pragma unroll
      for (int r2 = 0; r2 < NREP; ++r2) {
        sacc += __hip_atomic_load(&st_prev[r2 * 64 + b], __ATOMIC_RELAXED,
                                  __HIP_MEMORY_SCOPE_AGENT);
        qacc += __hip_atomic_load(&st_prev[NREP * 64 + r2 * 64 + b], __ATOMIC_RELAXED,
                                  __HIP_MEMORY_SCOPE_AGENT);
      }
    }

    f32x2 acc_ih[4] = {{0, 0}, {0, 0}, {0, 0}, {0, 0}};
    f32x2 acc_hh[4] = {{0, 0}, {0, 0}, {0, 0}, {0, 0}};
    gather8(meta_ih, s0i, ni, (const char*)(xt + (size_t)t * II * BB) + l * 16, acc_ih);
    if (t)
      gather8(meta_hh, s0h, nh, (const char*)(A + (size_t)(t - 1) * HD * BB) + l * 16, acc_hh);

#pragma unroll
    for (int j = 0; j < 4; ++j) {
#pragma unroll
      for (int d = 8; d < 64; d <<= 1) {
        acc_ih[j].x += __shfl_xor(acc_ih[j].x, d);
        acc_ih[j].y += __shfl_xor(acc_ih[j].y, d);
        acc_hh[j].x += __shfl_xor(acc_hh[j].x, d);
        acc_hh[j].y += __shfl_xor(acc_hh[j].y, d);
      }
    }
    if (lane < 8) {
#pragma unroll
      for (int j = 0; j < 4; ++j) {
        epil[w][0][lane * 8 + 2 * j] = acc_ih[j].x;
        epil[w][0][lane * 8 + 2 * j + 1] = acc_ih[j].y;
        epil[w][1][lane * 8 + 2 * j] = acc_hh[j].x;
        epil[w][1][lane * 8 + 2 * j + 1] = acc_hh[j].y;
      }
    }
    if (tid < 64) { s_sum[tid] = 0.f; s_sq[tid] = 0.f; }
    if (t && tid >= 64 && tid < 128) {
      int b = tid - 64;
      float mu = sacc * (1.0f / HD);
      float var = fmaxf(qacc * (1.0f / HD) - mu * mu, 0.0f);
      s_mu[b] = mu;
      s_rs[b] = rsqrtf(var + LN_EPS);
    }
    __syncthreads();

    float S_ih = epil[w][0][lane], S_hh = epil[w][1][lane];
    float pre = t ? S_ih + s_rs[lane] * (S_hh - s_mu[lane] * rvg) + (bsum + rvb)
                  : S_ih + bsum;
    float h = 1.0f - 2.0f / (__expf(2.0f * pre) + 1.0f);   // tanh
    A[(size_t)t * HD * BB + (size_t)row * BB + lane] = (u16)f2bf_bits(h);
    atomicAdd(&s_sum[lane], h);
    atomicAdd(&s_sq[lane], h * h);
    __syncthreads();
    if (tid < 64) {
      float* st_cur = stats + (size_t)t * (2 * NREP * 64);
      atomicAdd(&st_cur[rep * 64 + tid], s_sum[tid]);
      atomicAdd(&st_cur[NREP * 64 + rep * 64 + tid], s_sq[tid]);
    }
    if (t != TT - 1) grid_bar(bar, (u32)(t + 1) * GRIDN);
  }
}

// ---------------- per-step fallback (R2-proven path) ----------------

__global__ __launch_bounds__(256) void k_step(
    const u32* __restrict__ meta_ih, const int* __restrict__ rp_ih,
    const u32* __restrict__ meta_hh, const int* __restrict__ rp_hh,
    const u16* __restrict__ xt_t, const u16* __restrict__ Aprev,
    u16* __restrict__ Acur,
    const float* __restrict__ st_prev, float* __restrict__ st_cur,
    const float* __restrict__ b_ih, const float* __restrict__ b_hh,
    const float* __restrict__ rowvg, const float* __restrict__ rowvb, int first) {
  __shared__ float s_mu[64], s_rs[64], s_sum[64], s_sq[64];
  __shared__ float epil[4][2][64];
  int tid = threadIdx.x;
  int w = tid >> 6, lane = tid & 63;
  if (tid < 64) { s_sum[tid] = 0.f; s_sq[tid] = 0.f; s_mu[tid] = 0.f; s_rs[tid] = 1.f; }
  __syncthreads();
  if (!first && tid >= 64 && tid < 128) {
    int b = tid - 64;
    float s = 0.f, q = 0.f;
#pragma unroll
    for (int r2 = 0; r2 < NREP; ++r2) {
      s += st_prev[r2 * 64 + b];
      q += st_prev[NREP * 64 + r2 * 64 + b];
    }
    float mu = s * (1.0f / HD);
    float var = fmaxf(q * (1.0f / HD) - mu * mu, 0.0f);
    s_mu[b] = mu;
    s_rs[b] = rsqrtf(var + LN_EPS);
  }
  __syncthreads();

  int row = blockIdx.x * 4 + w;
  int l = lane & 7;
  f32x2 acc_ih[4] = {{0,0},{0,0},{0,0},{0,0}};
  f32x2 acc_hh[4] = {{0,0},{0,0},{0,0},{0,0}};
  {
    int s0 = rp_ih[row];
    int n = (rp_ih[row + 1] - s0) >> 3;
    gather8(meta_ih, s0, n, (const char*)xt_t + l * 16, acc_ih);
  }
  if (!first) {
    int s0 = rp_hh[row];
    int n = (rp_hh[row + 1] - s0) >> 3;
    gather8(meta_hh, s0, n, (const char*)Aprev + l * 16, acc_hh);
  }
#pragma unroll
  for (int j = 0; j < 4; ++j) {
#pragma unroll
    for (int d = 8; d < 64; d <<= 1) {
      acc_ih[j].x += __shfl_xor(acc_ih[j].x, d);
      acc_ih[j].y += __shfl_xor(acc_ih[j].y, d);
      acc_hh[j].x += __shfl_xor(acc_hh[j].x, d);
      acc_hh[j].y += __shfl_xor(acc_hh[j].y, d);
    }
  }
  if (lane < 8) {
#pragma unroll
    for (int j = 0; j < 4; ++j) {
      epil[w][0][lane * 8 + 2 * j] = acc_ih[j].x;
      epil[w][0][lane * 8 + 2 * j + 1] = acc_ih[j].y;
      epil[w][1][lane * 8 + 2 * j] = acc_hh[j].x;
      epil[w][1][lane * 8 + 2 * j + 1] = acc_hh[j].y;
    }
  }
  __syncthreads();
  float S_ih = epil[w][0][lane], S_hh = epil[w][1][lane];
  float bih = b_ih[row], bhh = b_hh[row];
  float pre;
  if (first)
    pre = S_ih + bih + bhh;
  else
    pre = S_ih + s_rs[lane] * (S_hh - s_mu[lane] * rowvg[row]) + (bih + bhh + rowvb[row]);
  float h = 1.0f - 2.0f / (__expf(2.0f * pre) + 1.0f);
  Acur[(size_t)row * BB + lane] = (u16)f2bf_bits(h);
  atomicAdd(&s_sum[lane], h);
  atomicAdd(&s_sq[lane], h * h);
  __syncthreads();
  if (tid < 64) {
    int rep = blockIdx.x & (NREP - 1);
    atomicAdd(&st_cur[rep * 64 + tid], s_sum[tid]);
    atomicAdd(&st_cur[NREP * 64 + rep * 64 + tid], s_sq[tid]);
  }
}

// ---------------- final output ----------------

__global__ __launch_bounds__(256) void k_out(const u16* __restrict__ A,
                                             const float* __restrict__ stats,
                                             const float* __restrict__ gamma,
                                             const float* __restrict__ beta,
                                             float* __restrict__ out) {
  __shared__ float s_mu[64], s_rs[64];
  __shared__ float tile[64][65];
  int t = blockIdx.x >> 6, r0 = (blockIdx.x & 63) << 6;
  int tid = threadIdx.x, w = tid >> 6, lane = tid & 63;
  const float* st = stats + (size_t)t * (2 * NREP * 64);
  if (tid < 64) {
    float s = 0.f, q = 0.f;
#pragma unroll
    for (int r2 = 0; r2 < NREP; ++r2) {
      s += st[r2 * 64 + tid];
      q += st[NREP * 64 + r2 * 64 + tid];
    }
    float mu = s * (1.0f / HD);
    float var = fmaxf(q * (1.0f / HD) - mu * mu, 0.0f);
    s_mu[tid] = mu;
    s_rs[tid] = rsqrtf(var + LN_EPS);
  }
  __syncthreads();
#pragma unroll
  for (int k = 0; k < 16; ++k) {
    int r = r0 + w * 16 + k;
    float a = __uint_as_float(((u32)A[((size_t)t * HD + r) * BB + lane]) << 16);
    float hn = (a - s_mu[lane]) * s_rs[lane] * gamma[r] + beta[r];
    tile[w * 16 + k][lane] = hn;
  }
  __syncthreads();
#pragma unroll
  for (int k = 0; k < 16; ++k) {
    int b = w * 16 + k;
    float v = tile[lane][b];
    out[((size_t)b * TT + t) * HD + r0 + lane] = v;
    if (t == TT - 1) out[(size_t)BB * TT * HD + (size_t)b * HD + r0 + lane] = v;
  }
}

// ---------------- host launch ----------------

extern "C" void kernel_launch(void* const* d_in, const int* in_sizes, int n_in,
                              void* d_out, int out_size, void* d_ws, size_t ws_size,
                              hipStream_t stream) {
  const float* x = (const float*)d_in[0];
  const int* ih_rows = (const int*)d_in[1];
  const int* ih_cols = (const int*)d_in[2];
  const float* ih_vals = (const float*)d_in[3];
  const int* hh_rows = (const int*)d_in[4];
  const int* hh_cols = (const int*)d_in[5];
  const float* hh_vals = (const float*)d_in[6];
  const float* b_ih = (const float*)d_in[7];
  const float* b_hh = (const float*)d_in[8];
  const float* gamma = (const float*)d_in[9];
  const float* beta = (const float*)d_in[10];

  char* ws = (char*)d_ws;
  u16* xt = (u16*)(ws + 0);                       // 16,777,216
  u16* A = (u16*)(ws + 16777216);                 // 67,108,864 (ends 83,886,080)
  u32* meta_ih = (u32*)(ws + 83886080);           // 1,179,904
  u32* meta_hh = (u32*)(ws + 85065984);           // 4,325,632  (end 89,391,616)
  float* stats = (float*)(ws + 89391616);         // 1,048,576  (end 90,440,192)
  float* rowvg = (float*)(ws + 90440192);         // 16,384
  float* rowvb = (float*)(ws + 90456576);         // 16,384
  int* rp_ih = (int*)(ws + 90472960);             // 16,640
  int* rp_hh = (int*)(ws + 90489600);             // 16,640  (end 90,506,240)
  u32* bar = (u32*)(ws + 90506240);               // 256

  // preprocessing scratch aliased into A region (dead before k_mega/k_step read A)
  char* scr = ws + 16777216;
  int* histG_ih = (int*)(scr + 0);                // 4,194,304
  int* histG_hh = (int*)(scr + 4194304);          // 4,194,304
  int* curG_ih = (int*)(scr + 8388608);           // 4,194,304
  int* curG_hh = (int*)(scr + 12582912);          // 4,194,304
  int* rowtot_ih = (int*)(scr + 16777216);        // 16,384
  int* rowtot_hh = (int*)(scr + 16793600);        // 16,384
  u16* metb_hh = (u16*)(scr + 16809984);          // 2,162,816

  hipMemsetAsync(scr + 16809984, 0, 2162816, stream);   // metb (incl. padding)
  hipMemsetAsync(ws + 83886080, 0, 6554112, stream);    // meta_ih + meta_hh + stats
  hipMemsetAsync(ws + 90506240, 0, 256, stream);        // barrier counter

  k_hist2<<<256, 256, 0, stream>>>(ih_rows, N_IH, histG_ih);
  k_hist2<<<256, 256, 0, stream>>>(hh_rows, N_HH, histG_hh);
  k_rowtot2<<<HD / 4, 256, 0, stream>>>(histG_ih, rowtot_ih);
  k_rowtot2<<<HD / 4, 256, 0, stream>>>(histG_hh, rowtot_hh);
  k_scan2<<<1, 64, 0, stream>>>(rowtot_ih, rp_ih);
  k_scan2<<<1, 64, 0, stream>>>(rowtot_hh, rp_hh);
  k_repbase2<<<HD / 4, 256, 0, stream>>>(histG_ih, rp_ih, curG_ih);
  k_repbase2<<<HD / 4, 256, 0, stream>>>(histG_hh, rp_hh, curG_hh);
  k_scatter2<<<256, 256, 0, stream>>>(ih_rows, ih_cols, ih_vals, N_IH, curG_ih,
                                      meta_ih, metb_hh, gamma, beta, 0);
  k_scatter2<<<256, 256, 0, stream>>>(hh_rows, hh_cols, hh_vals, N_HH, curG_hh,
                                      meta_hh, metb_hh, gamma, beta, 1);
  k_rvred2<<<HD / 4, 256, 0, stream>>>(meta_hh, metb_hh, rp_hh, rowvg, rowvb);
  k_xt<<<TT * (II / 64), 256, 0, stream>>>(x, xt);

  void* args[] = {(void*)&meta_ih, (void*)&rp_ih, (void*)&meta_hh, (void*)&rp_hh,
                  (void*)&xt, (void*)&A, (void*)&stats, (void*)&b_ih, (void*)&b_hh,
                  (void*)&rowvg, (void*)&rowvb, (void*)&bar};
  hipError_t err = hipLaunchCooperativeKernel(reinterpret_cast<void*>(k_mega),
                                              dim3(GRIDN), dim3(256), args, 0, stream);
  if (err != hipSuccess) {
    // fallback: proven per-step path
    for (int t = 0; t < TT; ++t) {
      const u16* xt_t = xt + (size_t)t * II * BB;
      const u16* Aprev = (t == 0) ? A : A + (size_t)(t - 1) * HD * BB;
      u16* Acur = A + (size_t)t * HD * BB;
      const float* st_prev = (t == 0) ? stats : stats + (size_t)(t - 1) * (2 * NREP * 64);
      float* st_cur = stats + (size_t)t * (2 * NREP * 64);
      k_step<<<HD / 4, 256, 0, stream>>>(meta_ih, rp_ih, meta_hh, rp_hh, xt_t, Aprev, Acur,
                                         st_prev, st_cur, b_ih, b_hh, rowvg, rowvb,
                                         (t == 0) ? 1 : 0);
    }
  }

  k_out<<<TT * (HD / 64), 256, 0, stream>>>(A, stats, gamma, beta, (float*)d_out);
}